// Round 8
// baseline (3705.170 us; speedup 1.0000x reference)
//
#include <hip/hip_runtime.h>
#include <stdint.h>

// MyVanillaRNN: B=64, T=512, INPUT=512, HIDDEN=1024
// out = concat( pre[B,T,H] (f32), h_final[B,H] (f32) )

typedef __attribute__((ext_vector_type(8))) short bf16x8;
typedef __attribute__((ext_vector_type(4))) float f32x4;
typedef unsigned long long u64;

__device__ __forceinline__ uint32_t f2bf(float f) {
    union { float f; uint32_t u; } v; v.f = f;
    return (v.u + 0x7FFFu + ((v.u >> 16) & 1u)) >> 16;   // RNE
}
__device__ __forceinline__ uint32_t pack2bf(float a, float b) {
    return f2bf(a) | (f2bf(b) << 16);
}
__device__ __forceinline__ float fast_tanh(float x) {
    const float xc = fminf(fmaxf(x, -15.f), 15.f);
    const float e  = __expf(2.f * xc);
    return (e - 1.f) * __builtin_amdgcn_rcpf(e + 1.f);
}

// ---------------------------------------------------------------------------
// Phase 1: out[m][n] = sum_k x[m][k]*Wx[n][k] + bx[n] + bh[n]
// M=32768, N=1024, K=512.  128x128 tile, BK=64, 4 waves, bf16 MFMA.
// ---------------------------------------------------------------------------
__global__ __launch_bounds__(256) void xproj_gemm(
    const float* __restrict__ x, const float* __restrict__ Wx,
    const float* __restrict__ bx, const float* __restrict__ bh,
    float* __restrict__ out)
{
    __shared__ __align__(16) uint8_t Ab[128 * 128];
    __shared__ __align__(16) uint8_t Bb[128 * 128];

    const int tid  = threadIdx.x;
    const int lane = tid & 63;
    const int wid  = tid >> 6;
    const int wm = wid >> 1, wn = wid & 1;
    const int m0 = (int)(blockIdx.x >> 3) * 128;
    const int n0 = (int)(blockIdx.x & 7) * 128;

    f32x4 acc[4][4];
    #pragma unroll
    for (int i = 0; i < 4; ++i)
        #pragma unroll
        for (int j = 0; j < 4; ++j) acc[i][j] = (f32x4){0.f, 0.f, 0.f, 0.f};

    const int sr = tid >> 4;
    const int sk = (tid & 15) << 2;

    for (int k0 = 0; k0 < 512; k0 += 64) {
        __syncthreads();
        #pragma unroll
        for (int p = 0; p < 8; ++p) {
            const int r = sr + p * 16;
            const float4 a = *(const float4*)(x  + (size_t)(m0 + r) * 512 + k0 + sk);
            const float4 b = *(const float4*)(Wx + (size_t)(n0 + r) * 512 + k0 + sk);
            const int byo = r * 128 + ((sk << 1) ^ ((r & 7) << 4));
            *(uint2*)(Ab + byo) = make_uint2(pack2bf(a.x, a.y), pack2bf(a.z, a.w));
            *(uint2*)(Bb + byo) = make_uint2(pack2bf(b.x, b.y), pack2bf(b.z, b.w));
        }
        __syncthreads();
        #pragma unroll
        for (int kt = 0; kt < 2; ++kt) {
            bf16x8 af[4], bfr[4];
            const int kb = (kt << 6) + ((lane >> 4) << 4);
            #pragma unroll
            for (int q = 0; q < 4; ++q) {
                const int ar = wm * 64 + q * 16 + (lane & 15);
                const int br = wn * 64 + q * 16 + (lane & 15);
                af[q]  = *(const bf16x8*)(Ab + ar * 128 + (kb ^ ((ar & 7) << 4)));
                bfr[q] = *(const bf16x8*)(Bb + br * 128 + (kb ^ ((br & 7) << 4)));
            }
            #pragma unroll
            for (int mt = 0; mt < 4; ++mt)
                #pragma unroll
                for (int nt = 0; nt < 4; ++nt)
                    acc[mt][nt] = __builtin_amdgcn_mfma_f32_16x16x32_bf16(
                        af[mt], bfr[nt], acc[mt][nt], 0, 0, 0);
        }
    }

    #pragma unroll
    for (int nt = 0; nt < 4; ++nt) {
        const int n = n0 + wn * 64 + nt * 16 + (lane & 15);
        const float bias = bx[n] + bh[n];
        #pragma unroll
        for (int mt = 0; mt < 4; ++mt) {
            const int mb = m0 + wm * 64 + mt * 16 + ((lane >> 4) << 2);
            #pragma unroll
            for (int i = 0; i < 4; ++i)
                out[(size_t)(mb + i) * 1024 + n] = acc[mt][nt][i] + bias;
        }
    }
}

// ---------------------------------------------------------------------------
// Phase 2: persistent scan. 8 groups (8 batches) x 8 blocks (128 H-cols).
// Block = 512 thr (8 waves); wave w: output cols [128nb+16w,+16), full
// K=1024, Wh register-resident. LDS padded >80KB -> 1 block/CU.
// h exchange: tagged words (bf16(h)<<16 | (t+1)) in d_ws; agent-scope relaxed
// atomics ONLY (rounds 3/5/7 proved sc0/plain-store "L2 fast paths" never
// deliver fresh data; the coherence point is memory-side).
// Poll structure (new this round):
//   - wave w in 1..7 polls ONLY chunk (nb+w)&7 (8 batches x 128 cols) with
//     8x u64 atomic loads/lane; stops as soon as ITS producer is visible.
//   - pipelined double-buffered rounds: set B issued before set A is
//     checked -> detection lag after visibility ~1 fabric RT, not 2.
//   - wave 0 has no poll (own chunk is LDS-resident from step t-1).
//   __syncthreads() assembles the block; MFMA over all 8 chunks follows.
// Own 128 cols never cross global (parity double-buffered LDS tile).
// xp software-pipelined one step ahead so the poll never waits on HBM.
// ---------------------------------------------------------------------------
__global__ __launch_bounds__(512, 1) void rnn_scan(
    const float* __restrict__ h0, const float* __restrict__ Wh,
    float* __restrict__ out, float* __restrict__ hfin,
    uint32_t* __restrict__ hbuf)   // [2][64][1024] tagged words
{
    // rows 0..7 (x2048B) per parity used; rest pads LDS > 80KB => 1 block/CU.
    __shared__ __align__(16) uint8_t htile[2][49152];

    const int tid  = threadIdx.x;
    const int lane = tid & 63;
    const int wid  = tid >> 6;          // 0..7
    const int g    = (int)blockIdx.x & 7;
    const int nb   = (int)blockIdx.x >> 3;
    const int gb0  = g * 8;             // batch base
    const int col  = nb * 128 + wid * 16 + (lane & 15);   // own output col
    const int r4b  = ((lane >> 4) & 1) << 2;              // 0/4 batch sub-base

    // --- Wh B-fragments: own col, full K. frag kt elem j <-> k=kt*32+(lane>>4)*8+j
    bf16x8 whf[32];
    {
        const float* wp = Wh + (size_t)col * 1024 + ((lane >> 4) << 3);
        #pragma unroll
        for (int kt = 0; kt < 32; ++kt) {
            const float4 w0 = *(const float4*)(wp + kt * 32);
            const float4 w1 = *(const float4*)(wp + kt * 32 + 4);
            bf16x8 f;
            f[0] = (short)f2bf(w0.x); f[1] = (short)f2bf(w0.y);
            f[2] = (short)f2bf(w0.z); f[3] = (short)f2bf(w0.w);
            f[4] = (short)f2bf(w1.x); f[5] = (short)f2bf(w1.y);
            f[6] = (short)f2bf(w1.z); f[7] = (short)f2bf(w1.w);
            whf[kt] = f;
        }
    }

    // --- init: publish own slice of h0 (tag 1, parity 0) + own LDS fill
    {
        const int colI = nb * 128 + lane * 2;   // two adjacent own cols
        const uint32_t u0 = f2bf(h0[(size_t)(gb0 + wid) * 1024 + colI]);
        const uint32_t u1 = f2bf(h0[(size_t)(gb0 + wid) * 1024 + colI + 1]);
        const int idx = (gb0 + wid) * 1024 + colI;
        __hip_atomic_store(&hbuf[idx],     (u0 << 16) | 1u, __ATOMIC_RELAXED, __HIP_MEMORY_SCOPE_AGENT);
        __hip_atomic_store(&hbuf[idx + 1], (u1 << 16) | 1u, __ATOMIC_RELAXED, __HIP_MEMORY_SCOPE_AGENT);
        *(uint32_t*)(htile[0] + wid * 2048 + ((colI * 2) ^ (wid << 4))) = u0 | (u1 << 16);
    }

    // --- this wave's poll assignment (wave 0: none)
    const int rbk = (nb + wid) & 7;                 // chunk this wave owns
    const int bl  = lane >> 3;                      // batch row 0..7
    const int c8  = (lane & 7) << 4;                // 16-col granule in chunk
    const int ib  = (gb0 + bl) * 1024 + rbk * 128 + c8;   // first word index
    const int sbase = bl * 2048;                    // LDS row base
    const int soff  = rbk * 256 + ((lane & 7) << 5);// byte off before XOR
    const int sxor  = bl << 4;

    // --- xp preload for t=0
    float xpv[4];
    #pragma unroll
    for (int i = 0; i < 4; ++i)
        xpv[i] = out[((size_t)(gb0 + r4b + i) * 512 + 0) * 1024 + col];

    for (int t = 0; t < 512; ++t) {
        const int cur = t & 1;
        uint32_t* const src = hbuf + cur * 65536;
        uint32_t* const dst = hbuf + (cur ^ 1) * 65536;
        const uint32_t exptag = (uint32_t)(t + 1);
        const uint32_t ntag   = exptag + 1;
        const u64 tag2 = ((u64)exptag << 32) | (u64)exptag;

        // --- phase A: per-wave chunk poll (waves 1..7), pipelined rounds
        if (wid > 0) {
            u64 va[8], vb[8];
            #pragma unroll
            for (int j = 0; j < 8; ++j)
                va[j] = __hip_atomic_load((const u64*)&src[ib + 2 * j],
                                          __ATOMIC_RELAXED, __HIP_MEMORY_SCOPE_AGENT);
            const u64* w = va;
            int rounds = 0;
            while (true) {
                // issue the other set before checking this one (pipelined)
                #pragma unroll
                for (int j = 0; j < 8; ++j)
                    vb[j] = __hip_atomic_load((const u64*)&src[ib + 2 * j],
                                              __ATOMIC_RELAXED, __HIP_MEMORY_SCOPE_AGENT);
                bool ok = true;
                #pragma unroll
                for (int j = 0; j < 8; ++j)
                    ok &= (((va[j] ^ tag2) & 0x0000FFFF0000FFFFull) == 0);
                if (ok) { w = va; break; }

                #pragma unroll
                for (int j = 0; j < 8; ++j)
                    va[j] = __hip_atomic_load((const u64*)&src[ib + 2 * j],
                                              __ATOMIC_RELAXED, __HIP_MEMORY_SCOPE_AGENT);
                ok = true;
                #pragma unroll
                for (int j = 0; j < 8; ++j)
                    ok &= (((vb[j] ^ tag2) & 0x0000FFFF0000FFFFull) == 0);
                if (ok) { w = vb; break; }
                if (++rounds > 512) __builtin_amdgcn_s_sleep(2);   // paranoia only
            }
            // stage this chunk's 16 bf16 (8x u32 pairs) into LDS
            #pragma unroll
            for (int j = 0; j < 8; ++j) {
                const uint32_t lo = (uint32_t)w[j];
                const uint32_t hi = (uint32_t)(w[j] >> 32);
                const uint32_t pk = (lo >> 16) | (hi & 0xFFFF0000u);
                *(uint32_t*)(htile[cur] + sbase + ((soff + 4 * j) ^ sxor)) = pk;
            }
        }
        __syncthreads();   // htile[cur] complete (7 staged chunks + own from t-1)

        // --- xp prefetch for NEXT step (off the poll's critical path)
        float xnext[4];
        if (t < 511) {
            #pragma unroll
            for (int i = 0; i < 4; ++i)
                xnext[i] = out[((size_t)(gb0 + r4b + i) * 512 + (t + 1)) * 1024 + col];
        }

        // --- phase B: acc = h . Wh[col]^T over full K, 4 interleaved chains
        f32x4 a0 = (f32x4){0.f,0.f,0.f,0.f}, a1 = a0, a2 = a0, a3 = a0;
        {
            const int b_  = lane & 7;
            const int kbx = (lane >> 4) << 4;
            const int swz = b_ << 4;
            const uint8_t* hb = htile[cur] + b_ * 2048;
            #pragma unroll
            for (int kt = 0; kt < 32; kt += 4) {
                const bf16x8 f0 = *(const bf16x8*)(hb + (((kt    ) * 64 + kbx) ^ swz));
                const bf16x8 f1 = *(const bf16x8*)(hb + (((kt + 1) * 64 + kbx) ^ swz));
                const bf16x8 f2 = *(const bf16x8*)(hb + (((kt + 2) * 64 + kbx) ^ swz));
                const bf16x8 f3 = *(const bf16x8*)(hb + (((kt + 3) * 64 + kbx) ^ swz));
                a0 = __builtin_amdgcn_mfma_f32_16x16x32_bf16(f0, whf[kt    ], a0, 0, 0, 0);
                a1 = __builtin_amdgcn_mfma_f32_16x16x32_bf16(f1, whf[kt + 1], a1, 0, 0, 0);
                a2 = __builtin_amdgcn_mfma_f32_16x16x32_bf16(f2, whf[kt + 2], a2, 0, 0, 0);
                a3 = __builtin_amdgcn_mfma_f32_16x16x32_bf16(f3, whf[kt + 3], a3, 0, 0, 0);
            }
        }

        // --- phase C: lanes<32 publish h (critical path); lanes>=32 (which
        // hold a duplicate C fragment) write out[] concurrently.
        float pre[4], hn[4];
        #pragma unroll
        for (int i = 0; i < 4; ++i) {
            pre[i] = ((a0[i] + a1[i]) + (a2[i] + a3[i])) + xpv[i];
            hn[i]  = fast_tanh(pre[i]);
        }
        if (lane < 32) {
            if (t < 511) {
                uint32_t hu[4];
                #pragma unroll
                for (int i = 0; i < 4; ++i) hu[i] = f2bf(hn[i]);
                #pragma unroll
                for (int i = 0; i < 4; ++i)
                    __hip_atomic_store(&dst[(gb0 + r4b + i) * 1024 + col], (hu[i] << 16) | ntag,
                                       __ATOMIC_RELAXED, __HIP_MEMORY_SCOPE_AGENT);
                // own slice -> next parity's LDS tile (never crosses global)
                #pragma unroll
                for (int i = 0; i < 4; ++i)
                    *(uint16_t*)(htile[cur ^ 1] + (r4b + i) * 2048 + ((col * 2) ^ ((r4b + i) << 4))) = (uint16_t)hu[i];
            }
        } else {
            #pragma unroll
            for (int i = 0; i < 4; ++i) {
                out[((size_t)(gb0 + r4b + i) * 512 + t) * 1024 + col] = pre[i];
                if (t == 511) hfin[(size_t)(gb0 + r4b + i) * 1024 + col] = hn[i];
            }
        }
        #pragma unroll
        for (int i = 0; i < 4; ++i) xpv[i] = xnext[i];
    }
}

// ---------------------------------------------------------------------------
extern "C" void kernel_launch(void* const* d_in, const int* in_sizes, int n_in,
                              void* d_out, int out_size, void* d_ws, size_t ws_size,
                              hipStream_t stream) {
    const float* x   = (const float*)d_in[0];   // [64,512,512]
    const float* h0_ = (const float*)d_in[1];   // [64,1024]
    const float* Wx  = (const float*)d_in[2];   // [1024,512]
    const float* bx  = (const float*)d_in[3];   // [1024]
    const float* Wh  = (const float*)d_in[4];   // [1024,1024]
    const float* bh  = (const float*)d_in[5];   // [1024]
    float* out  = (float*)d_out;                         // [64,512,1024] pre
    float* hfin = out + (size_t)64 * 512 * 1024;         // [64,1024]
    uint32_t* hbuf = (uint32_t*)d_ws;                    // [2][64][1024] u32 = 512 KB

    // invalidate all tags (0xFFFF matches no step tag 1..513)
    hipMemsetAsync(d_ws, 0xFF, (size_t)2 * 64 * 1024 * sizeof(uint32_t), stream);

    xproj_gemm<<<dim3(2048), dim3(256), 0, stream>>>(x, Wx, bx, bh, out);
    rnn_scan<<<dim3(64), dim3(512), 0, stream>>>(h0_, Wh, out, hfin, hbuf);
}

// Round 9
// 1942.250 us; speedup vs baseline: 1.9077x; 1.9077x over previous
//
#include <hip/hip_runtime.h>
#include <stdint.h>

// MyVanillaRNN: B=64, T=512, INPUT=512, HIDDEN=1024
// out = concat( pre[B,T,H] (f32), h_final[B,H] (f32) )

typedef __attribute__((ext_vector_type(8))) short bf16x8;
typedef __attribute__((ext_vector_type(4))) float f32x4;

__device__ __forceinline__ uint32_t f2bf(float f) {
    union { float f; uint32_t u; } v; v.f = f;
    return (v.u + 0x7FFFu + ((v.u >> 16) & 1u)) >> 16;   // RNE
}
__device__ __forceinline__ uint32_t pack2bf(float a, float b) {
    return f2bf(a) | (f2bf(b) << 16);
}
__device__ __forceinline__ float fast_tanh(float x) {
    const float xc = fminf(fmaxf(x, -15.f), 15.f);
    const float e  = __expf(2.f * xc);
    return (e - 1.f) * __builtin_amdgcn_rcpf(e + 1.f);
}

// ---------------------------------------------------------------------------
// Phase 1: out[m][n] = sum_k x[m][k]*Wx[n][k] + bx[n] + bh[n]
// M=32768, N=1024, K=512.  128x128 tile, BK=64, 4 waves, bf16 MFMA.
// ---------------------------------------------------------------------------
__global__ __launch_bounds__(256) void xproj_gemm(
    const float* __restrict__ x, const float* __restrict__ Wx,
    const float* __restrict__ bx, const float* __restrict__ bh,
    float* __restrict__ out)
{
    __shared__ __align__(16) uint8_t Ab[128 * 128];
    __shared__ __align__(16) uint8_t Bb[128 * 128];

    const int tid  = threadIdx.x;
    const int lane = tid & 63;
    const int wid  = tid >> 6;
    const int wm = wid >> 1, wn = wid & 1;
    const int m0 = (int)(blockIdx.x >> 3) * 128;
    const int n0 = (int)(blockIdx.x & 7) * 128;

    f32x4 acc[4][4];
    #pragma unroll
    for (int i = 0; i < 4; ++i)
        #pragma unroll
        for (int j = 0; j < 4; ++j) acc[i][j] = (f32x4){0.f, 0.f, 0.f, 0.f};

    const int sr = tid >> 4;
    const int sk = (tid & 15) << 2;

    for (int k0 = 0; k0 < 512; k0 += 64) {
        __syncthreads();
        #pragma unroll
        for (int p = 0; p < 8; ++p) {
            const int r = sr + p * 16;
            const float4 a = *(const float4*)(x  + (size_t)(m0 + r) * 512 + k0 + sk);
            const float4 b = *(const float4*)(Wx + (size_t)(n0 + r) * 512 + k0 + sk);
            const int byo = r * 128 + ((sk << 1) ^ ((r & 7) << 4));
            *(uint2*)(Ab + byo) = make_uint2(pack2bf(a.x, a.y), pack2bf(a.z, a.w));
            *(uint2*)(Bb + byo) = make_uint2(pack2bf(b.x, b.y), pack2bf(b.z, b.w));
        }
        __syncthreads();
        #pragma unroll
        for (int kt = 0; kt < 2; ++kt) {
            bf16x8 af[4], bfr[4];
            const int kb = (kt << 6) + ((lane >> 4) << 4);
            #pragma unroll
            for (int q = 0; q < 4; ++q) {
                const int ar = wm * 64 + q * 16 + (lane & 15);
                const int br = wn * 64 + q * 16 + (lane & 15);
                af[q]  = *(const bf16x8*)(Ab + ar * 128 + (kb ^ ((ar & 7) << 4)));
                bfr[q] = *(const bf16x8*)(Bb + br * 128 + (kb ^ ((br & 7) << 4)));
            }
            #pragma unroll
            for (int mt = 0; mt < 4; ++mt)
                #pragma unroll
                for (int nt = 0; nt < 4; ++nt)
                    acc[mt][nt] = __builtin_amdgcn_mfma_f32_16x16x32_bf16(
                        af[mt], bfr[nt], acc[mt][nt], 0, 0, 0);
        }
    }

    #pragma unroll
    for (int nt = 0; nt < 4; ++nt) {
        const int n = n0 + wn * 64 + nt * 16 + (lane & 15);
        const float bias = bx[n] + bh[n];
        #pragma unroll
        for (int mt = 0; mt < 4; ++mt) {
            const int mb = m0 + wm * 64 + mt * 16 + ((lane >> 4) << 2);
            #pragma unroll
            for (int i = 0; i < 4; ++i)
                out[(size_t)(mb + i) * 1024 + n] = acc[mt][nt][i] + bias;
        }
    }
}

// ---------------------------------------------------------------------------
// Phase 2: persistent scan. 8 groups (8 batches) x 8 blocks (128 H-cols).
// Identical skeleton to round 6 (best so far) EXCEPT the handoff protocol:
//   producer: payload stores (tagged words, agent scope) -> s_waitcnt
//   vmcnt(0) (payload ACKed at coherence point) -> __syncthreads ->
//   tid==0 stores ONE tag word for this (group, block, parity).
//   consumer: polls only the 7 remote TAG words (lanes 0..6 per wave,
//   ~3.6K reqs/round chip-wide vs round-6's ~460K payload-poll flood),
//   then reads its 14 payload words ONCE. Embedded per-word tags are
//   re-verified (paranoia loop) so correctness never rests on ordering.
// Own 128 cols never cross global (parity double-buffered LDS tile).
// xp software-pipelined one step ahead. LDS padded >80KB -> 1 block/CU.
// ---------------------------------------------------------------------------
__global__ __launch_bounds__(512, 1) void rnn_scan(
    const float* __restrict__ h0, const float* __restrict__ Wh,
    float* __restrict__ out, float* __restrict__ hfin,
    uint32_t* __restrict__ hbuf,   // [2][64][1024] tagged payload words
    uint32_t* __restrict__ tagb)   // [2][8 grp][8 blk] x16-word padding
{
    // rows 0..7 (x2048B) per parity used; rest pads LDS > 80KB => 1 block/CU.
    __shared__ __align__(16) uint8_t htile[2][49152];

    const int tid  = threadIdx.x;
    const int lane = tid & 63;
    const int wid  = tid >> 6;          // 0..7
    const int g    = (int)blockIdx.x & 7;
    const int nb   = (int)blockIdx.x >> 3;
    const int gb0  = g * 8;             // batch base
    const int col  = nb * 128 + wid * 16 + (lane & 15);   // own output col
    const int r4b  = ((lane >> 4) & 1) << 2;              // 0/4 batch sub-base

    // --- Wh B-fragments: own col, full K. frag kt elem j <-> k=kt*32+(lane>>4)*8+j
    bf16x8 whf[32];
    {
        const float* wp = Wh + (size_t)col * 1024 + ((lane >> 4) << 3);
        #pragma unroll
        for (int kt = 0; kt < 32; ++kt) {
            const float4 w0 = *(const float4*)(wp + kt * 32);
            const float4 w1 = *(const float4*)(wp + kt * 32 + 4);
            bf16x8 f;
            f[0] = (short)f2bf(w0.x); f[1] = (short)f2bf(w0.y);
            f[2] = (short)f2bf(w0.z); f[3] = (short)f2bf(w0.w);
            f[4] = (short)f2bf(w1.x); f[5] = (short)f2bf(w1.y);
            f[6] = (short)f2bf(w1.z); f[7] = (short)f2bf(w1.w);
            whf[kt] = f;
        }
    }

    // --- init: publish own slice of h0 (tag 1, parity 0) + own LDS fill,
    // then ACK + barrier + block tag.
    {
        const int colI = nb * 128 + lane * 2;   // two adjacent own cols
        const uint32_t u0 = f2bf(h0[(size_t)(gb0 + wid) * 1024 + colI]);
        const uint32_t u1 = f2bf(h0[(size_t)(gb0 + wid) * 1024 + colI + 1]);
        const int idx = (gb0 + wid) * 1024 + colI;
        __hip_atomic_store(&hbuf[idx],     (u0 << 16) | 1u, __ATOMIC_RELAXED, __HIP_MEMORY_SCOPE_AGENT);
        __hip_atomic_store(&hbuf[idx + 1], (u1 << 16) | 1u, __ATOMIC_RELAXED, __HIP_MEMORY_SCOPE_AGENT);
        *(uint32_t*)(htile[0] + wid * 2048 + ((colI * 2) ^ (wid << 4))) = u0 | (u1 << 16);
        asm volatile("s_waitcnt vmcnt(0)" ::: "memory");   // payload ACKed
        __syncthreads();
        if (tid == 0)
            __hip_atomic_store(&tagb[((0 << 6) + (g << 3) + nb) << 4], 1u,
                               __ATOMIC_RELAXED, __HIP_MEMORY_SCOPE_AGENT);
    }

    // --- poll indices: 7 remote blocks x 2 payload words; batch row = wid
    const int pb  = wid;
    const int pc0 = lane * 2;
    int ridx[7];
    #pragma unroll
    for (int r = 0; r < 7; ++r) {
        const int rbk = (nb + 1 + r) & 7;
        ridx[r] = (gb0 + pb) * 1024 + rbk * 128 + pc0;
    }
    // this lane's tag word (lanes 0..6 poll; others inert)
    const int myrbk  = (nb + 1 + (lane < 7 ? lane : 0)) & 7;
    const int tbase  = ((g << 3) + myrbk) << 4;

    // --- xp preload for t=0
    float xpv[4];
    #pragma unroll
    for (int i = 0; i < 4; ++i)
        xpv[i] = out[((size_t)(gb0 + r4b + i) * 512 + 0) * 1024 + col];

    for (int t = 0; t < 512; ++t) {
        const int cur = t & 1;
        uint32_t* const src = hbuf + cur * 65536;
        uint32_t* const dst = hbuf + (cur ^ 1) * 65536;
        const uint32_t exptag = (uint32_t)(t + 1);
        const uint32_t ntag   = exptag + 1;

        // --- phase A1: poll the 7 remote TAG words (per wave, lanes 0..6)
        {
            const uint32_t* tp = &tagb[(cur << 10) + tbase];
            int rounds = 0;
            while (true) {
                uint32_t tv = exptag;
                if (lane < 7)
                    tv = __hip_atomic_load(tp, __ATOMIC_RELAXED, __HIP_MEMORY_SCOPE_AGENT);
                if (__all(tv == exptag)) break;
                if (++rounds > 256) __builtin_amdgcn_s_sleep(2);   // paranoia only
            }
        }

        // --- phase A2: single payload read (fresh by ACK-before-tag order);
        // embedded tags re-verified as a correctness backstop.
        uint32_t v[14];
        {
            #pragma unroll
            for (int r = 0; r < 7; ++r) {
                v[2 * r]     = __hip_atomic_load(&src[ridx[r]],     __ATOMIC_RELAXED, __HIP_MEMORY_SCOPE_AGENT);
                v[2 * r + 1] = __hip_atomic_load(&src[ridx[r] + 1], __ATOMIC_RELAXED, __HIP_MEMORY_SCOPE_AGENT);
            }
            int rounds = 0;
            while (true) {
                bool ok = true;
                #pragma unroll
                for (int p = 0; p < 14; ++p) ok &= ((v[p] & 0xFFFFu) == exptag);
                if (ok) break;
                #pragma unroll
                for (int r = 0; r < 7; ++r) {
                    v[2 * r]     = __hip_atomic_load(&src[ridx[r]],     __ATOMIC_RELAXED, __HIP_MEMORY_SCOPE_AGENT);
                    v[2 * r + 1] = __hip_atomic_load(&src[ridx[r] + 1], __ATOMIC_RELAXED, __HIP_MEMORY_SCOPE_AGENT);
                }
                if (++rounds > 256) __builtin_amdgcn_s_sleep(2);
            }
        }
        // stage remote h into this parity's LDS tile
        #pragma unroll
        for (int r = 0; r < 7; ++r) {
            const int rbk = (nb + 1 + r) & 7;
            const int c0  = rbk * 128 + pc0;
            const uint32_t pk = (v[2 * r] >> 16) | (v[2 * r + 1] & 0xFFFF0000u);
            *(uint32_t*)(htile[cur] + pb * 2048 + ((c0 * 2) ^ (pb << 4))) = pk;
        }
        __syncthreads();   // htile[cur] complete (remote staged + own from t-1)

        // --- phase B: acc = h . Wh[col]^T over full K, 4 interleaved chains
        f32x4 a0 = (f32x4){0.f,0.f,0.f,0.f}, a1 = a0, a2 = a0, a3 = a0;
        {
            const int b_  = lane & 7;
            const int kbx = (lane >> 4) << 4;
            const int swz = b_ << 4;
            const uint8_t* hb = htile[cur] + b_ * 2048;
            #pragma unroll
            for (int kt = 0; kt < 32; kt += 4) {
                const bf16x8 f0 = *(const bf16x8*)(hb + (((kt    ) * 64 + kbx) ^ swz));
                const bf16x8 f1 = *(const bf16x8*)(hb + (((kt + 1) * 64 + kbx) ^ swz));
                const bf16x8 f2 = *(const bf16x8*)(hb + (((kt + 2) * 64 + kbx) ^ swz));
                const bf16x8 f3 = *(const bf16x8*)(hb + (((kt + 3) * 64 + kbx) ^ swz));
                a0 = __builtin_amdgcn_mfma_f32_16x16x32_bf16(f0, whf[kt    ], a0, 0, 0, 0);
                a1 = __builtin_amdgcn_mfma_f32_16x16x32_bf16(f1, whf[kt + 1], a1, 0, 0, 0);
                a2 = __builtin_amdgcn_mfma_f32_16x16x32_bf16(f2, whf[kt + 2], a2, 0, 0, 0);
                a3 = __builtin_amdgcn_mfma_f32_16x16x32_bf16(f3, whf[kt + 3], a3, 0, 0, 0);
            }
        }

        // --- phase C: finalize. Publish payload -> ACK -> barrier -> tag.
        // out[]/hfin/xnext kept OFF the publish critical path.
        float pre[4], hn[4];
        #pragma unroll
        for (int i = 0; i < 4; ++i) {
            pre[i] = ((a0[i] + a1[i]) + (a2[i] + a3[i])) + xpv[i];
            hn[i]  = fast_tanh(pre[i]);
        }
        if (t < 511) {
            if (lane < 32) {
                uint32_t hu[4];
                #pragma unroll
                for (int i = 0; i < 4; ++i) hu[i] = f2bf(hn[i]);
                #pragma unroll
                for (int i = 0; i < 4; ++i)
                    __hip_atomic_store(&dst[(gb0 + r4b + i) * 1024 + col], (hu[i] << 16) | ntag,
                                       __ATOMIC_RELAXED, __HIP_MEMORY_SCOPE_AGENT);
                // own slice -> next parity's LDS tile (never crosses global)
                #pragma unroll
                for (int i = 0; i < 4; ++i)
                    *(uint16_t*)(htile[cur ^ 1] + (r4b + i) * 2048 + ((col * 2) ^ ((r4b + i) << 4))) = (uint16_t)hu[i];
            }
            asm volatile("s_waitcnt vmcnt(0)" ::: "memory");   // payload ACKed
            __syncthreads();                                    // all 8 waves ACKed
            if (tid == 0)
                __hip_atomic_store(&tagb[(((cur ^ 1) << 6) + (g << 3) + nb) << 4], ntag,
                                   __ATOMIC_RELAXED, __HIP_MEMORY_SCOPE_AGENT);
        }
        if (lane >= 32) {
            #pragma unroll
            for (int i = 0; i < 4; ++i) {
                out[((size_t)(gb0 + r4b + i) * 512 + t) * 1024 + col] = pre[i];
                if (t == 511) hfin[(size_t)(gb0 + r4b + i) * 1024 + col] = hn[i];
            }
        }
        // --- xp prefetch for NEXT step (after tag store; consumed next fin.)
        if (t < 511) {
            float xnext[4];
            #pragma unroll
            for (int i = 0; i < 4; ++i)
                xnext[i] = out[((size_t)(gb0 + r4b + i) * 512 + (t + 1)) * 1024 + col];
            #pragma unroll
            for (int i = 0; i < 4; ++i) xpv[i] = xnext[i];
        }
    }
}

// ---------------------------------------------------------------------------
extern "C" void kernel_launch(void* const* d_in, const int* in_sizes, int n_in,
                              void* d_out, int out_size, void* d_ws, size_t ws_size,
                              hipStream_t stream) {
    const float* x   = (const float*)d_in[0];   // [64,512,512]
    const float* h0_ = (const float*)d_in[1];   // [64,1024]
    const float* Wx  = (const float*)d_in[2];   // [1024,512]
    const float* bx  = (const float*)d_in[3];   // [1024]
    const float* Wh  = (const float*)d_in[4];   // [1024,1024]
    const float* bh  = (const float*)d_in[5];   // [1024]
    float* out  = (float*)d_out;                         // [64,512,1024] pre
    float* hfin = out + (size_t)64 * 512 * 1024;         // [64,1024]

    uint32_t* hbuf = (uint32_t*)d_ws;                    // [2][64][1024] = 512 KB
    uint32_t* tagb = hbuf + 2 * 65536;                   // [2][8][8] x16 pad = 8 KB

    // invalidate payload tags AND block tags (0xFF.. matches no tag 1..513)
    hipMemsetAsync(d_ws, 0xFF,
                   ((size_t)2 * 65536 + 2048) * sizeof(uint32_t), stream);

    xproj_gemm<<<dim3(2048), dim3(256), 0, stream>>>(x, Wx, bx, bh, out);
    rnn_scan<<<dim3(64), dim3(512), 0, stream>>>(h0_, Wh, out, hfin, hbuf, tagb);
}

// Round 11
// 1518.457 us; speedup vs baseline: 2.4401x; 1.2791x over previous
//
#include <hip/hip_runtime.h>
#include <stdint.h>

// MyVanillaRNN: B=64, T=512, INPUT=512, HIDDEN=1024
// out = concat( pre[B,T,H] (f32), h_final[B,H] (f32) )

typedef __attribute__((ext_vector_type(8))) short bf16x8;
typedef __attribute__((ext_vector_type(4))) float f32x4;

__device__ __forceinline__ uint32_t f2bf(float f) {
    union { float f; uint32_t u; } v; v.f = f;
    return (v.u + 0x7FFFu + ((v.u >> 16) & 1u)) >> 16;   // RNE
}
__device__ __forceinline__ uint32_t pack2bf(float a, float b) {
    return f2bf(a) | (f2bf(b) << 16);
}
__device__ __forceinline__ float fast_tanh(float x) {
    const float xc = fminf(fmaxf(x, -15.f), 15.f);
    const float e  = __expf(2.f * xc);
    return (e - 1.f) * __builtin_amdgcn_rcpf(e + 1.f);
}

// ---------------------------------------------------------------------------
// Phase 1: out[m][n] = sum_k x[m][k]*Wx[n][k] + bx[n] + bh[n]
// M=32768, N=1024, K=512.  128x128 tile, BK=64, 4 waves, bf16 MFMA.
// ---------------------------------------------------------------------------
__global__ __launch_bounds__(256) void xproj_gemm(
    const float* __restrict__ x, const float* __restrict__ Wx,
    const float* __restrict__ bx, const float* __restrict__ bh,
    float* __restrict__ out)
{
    __shared__ __align__(16) uint8_t Ab[128 * 128];
    __shared__ __align__(16) uint8_t Bb[128 * 128];

    const int tid  = threadIdx.x;
    const int lane = tid & 63;
    const int wid  = tid >> 6;
    const int wm = wid >> 1, wn = wid & 1;
    const int m0 = (int)(blockIdx.x >> 3) * 128;
    const int n0 = (int)(blockIdx.x & 7) * 128;

    f32x4 acc[4][4];
    #pragma unroll
    for (int i = 0; i < 4; ++i)
        #pragma unroll
        for (int j = 0; j < 4; ++j) acc[i][j] = (f32x4){0.f, 0.f, 0.f, 0.f};

    const int sr = tid >> 4;
    const int sk = (tid & 15) << 2;

    for (int k0 = 0; k0 < 512; k0 += 64) {
        __syncthreads();
        #pragma unroll
        for (int p = 0; p < 8; ++p) {
            const int r = sr + p * 16;
            const float4 a = *(const float4*)(x  + (size_t)(m0 + r) * 512 + k0 + sk);
            const float4 b = *(const float4*)(Wx + (size_t)(n0 + r) * 512 + k0 + sk);
            const int byo = r * 128 + ((sk << 1) ^ ((r & 7) << 4));
            *(uint2*)(Ab + byo) = make_uint2(pack2bf(a.x, a.y), pack2bf(a.z, a.w));
            *(uint2*)(Bb + byo) = make_uint2(pack2bf(b.x, b.y), pack2bf(b.z, b.w));
        }
        __syncthreads();
        #pragma unroll
        for (int kt = 0; kt < 2; ++kt) {
            bf16x8 af[4], bfr[4];
            const int kb = (kt << 6) + ((lane >> 4) << 4);
            #pragma unroll
            for (int q = 0; q < 4; ++q) {
                const int ar = wm * 64 + q * 16 + (lane & 15);
                const int br = wn * 64 + q * 16 + (lane & 15);
                af[q]  = *(const bf16x8*)(Ab + ar * 128 + (kb ^ ((ar & 7) << 4)));
                bfr[q] = *(const bf16x8*)(Bb + br * 128 + (kb ^ ((br & 7) << 4)));
            }
            #pragma unroll
            for (int mt = 0; mt < 4; ++mt)
                #pragma unroll
                for (int nt = 0; nt < 4; ++nt)
                    acc[mt][nt] = __builtin_amdgcn_mfma_f32_16x16x32_bf16(
                        af[mt], bfr[nt], acc[mt][nt], 0, 0, 0);
        }
    }

    #pragma unroll
    for (int nt = 0; nt < 4; ++nt) {
        const int n = n0 + wn * 64 + nt * 16 + (lane & 15);
        const float bias = bx[n] + bh[n];
        #pragma unroll
        for (int mt = 0; mt < 4; ++mt) {
            const int mb = m0 + wm * 64 + mt * 16 + ((lane >> 4) << 2);
            #pragma unroll
            for (int i = 0; i < 4; ++i)
                out[(size_t)(mb + i) * 1024 + n] = acc[mt][nt][i] + bias;
        }
    }
}

// ---------------------------------------------------------------------------
// Phase 2: persistent scan. 8 groups (8 batches) x 8 blocks (128 H-cols).
// EXACT round-6 structure (best verified: 1480us) with ONE change:
//   htile row stride 2064B (516 words == 4-bank drift/row, 16B-aligned),
//   no XOR. Bank arithmetic: MFMA b128 reads get bank-start 4*((r+q)%8),
//   each residue 4x with 2-lane broadcast = the 256-access/32-bank lower
//   bound (bank-optimal). Round-6's XOR-2048 was 8-way on quads
//   (measured 3.36e7 conflict-cycles/dispatch).
// h exchange: tagged words (bf16(h)<<16 | (t+1)); relaxed agent-scope
// atomics only (rounds 3/5/7: sc0/plain-store L2 paths never deliver;
// round 9: ACK+tag 2-hop serializes; round 10: asm streaming poll is
// compiler-unsafe). Tight serial agent poll is the proven optimum so far.
// Own 128 cols never cross global (parity double-buffered LDS tile).
// xp software-pipelined one step ahead. LDS padded >80KB -> 1 block/CU.
// ---------------------------------------------------------------------------
__global__ __launch_bounds__(512, 1) void rnn_scan(
    const float* __restrict__ h0, const float* __restrict__ Wh,
    float* __restrict__ out, float* __restrict__ hfin,
    uint32_t* __restrict__ hbuf)   // [2][64][1024] tagged words
{
    // rows 0..7 (x2064B) per parity used; rest pads LDS > 80KB => 1 block/CU.
    __shared__ __align__(16) uint8_t htile[2][49152];

    const int tid  = threadIdx.x;
    const int lane = tid & 63;
    const int wid  = tid >> 6;          // 0..7
    const int g    = (int)blockIdx.x & 7;
    const int nb   = (int)blockIdx.x >> 3;
    const int gb0  = g * 8;             // batch base
    const int col  = nb * 128 + wid * 16 + (lane & 15);   // own output col
    const int r4b  = ((lane >> 4) & 1) << 2;              // 0/4 batch sub-base

    // --- Wh B-fragments: own col, full K. frag kt elem j <-> k=kt*32+(lane>>4)*8+j
    bf16x8 whf[32];
    {
        const float* wp = Wh + (size_t)col * 1024 + ((lane >> 4) << 3);
        #pragma unroll
        for (int kt = 0; kt < 32; ++kt) {
            const float4 w0 = *(const float4*)(wp + kt * 32);
            const float4 w1 = *(const float4*)(wp + kt * 32 + 4);
            bf16x8 f;
            f[0] = (short)f2bf(w0.x); f[1] = (short)f2bf(w0.y);
            f[2] = (short)f2bf(w0.z); f[3] = (short)f2bf(w0.w);
            f[4] = (short)f2bf(w1.x); f[5] = (short)f2bf(w1.y);
            f[6] = (short)f2bf(w1.z); f[7] = (short)f2bf(w1.w);
            whf[kt] = f;
        }
    }

    // --- init: publish own slice of h0 (tag 1, parity 0) + own LDS fill
    {
        const int colI = nb * 128 + lane * 2;   // two adjacent own cols
        const uint32_t u0 = f2bf(h0[(size_t)(gb0 + wid) * 1024 + colI]);
        const uint32_t u1 = f2bf(h0[(size_t)(gb0 + wid) * 1024 + colI + 1]);
        const int idx = (gb0 + wid) * 1024 + colI;
        __hip_atomic_store(&hbuf[idx],     (u0 << 16) | 1u, __ATOMIC_RELAXED, __HIP_MEMORY_SCOPE_AGENT);
        __hip_atomic_store(&hbuf[idx + 1], (u1 << 16) | 1u, __ATOMIC_RELAXED, __HIP_MEMORY_SCOPE_AGENT);
        *(uint32_t*)(htile[0] + wid * 2064 + colI * 2) = u0 | (u1 << 16);
    }

    // --- poll indices: 7 remote blocks x 2 words; batch row = wid
    const int pb  = wid;
    const int pc0 = lane * 2;
    int ridx[7];
    #pragma unroll
    for (int r = 0; r < 7; ++r) {
        const int rbk = (nb + 1 + r) & 7;
        ridx[r] = (gb0 + pb) * 1024 + rbk * 128 + pc0;
    }

    // --- xp preload for t=0 (all lanes; lanes>=32 mirror lanes<32)
    float xpv[4];
    #pragma unroll
    for (int i = 0; i < 4; ++i)
        xpv[i] = out[((size_t)(gb0 + r4b + i) * 512 + 0) * 1024 + col];

    for (int t = 0; t < 512; ++t) {
        const int cur = t & 1;
        uint32_t* const src = hbuf + cur * 65536;
        uint32_t* const dst = hbuf + (cur ^ 1) * 65536;
        const uint32_t exptag = (uint32_t)(t + 1);
        const uint32_t ntag   = exptag + 1;

        // --- phase A: poll the 7 remote blocks' slices (agent loads, tight)
        uint32_t v[14];
        int rounds = 0;
        while (true) {
            #pragma unroll
            for (int r = 0; r < 7; ++r) {
                v[2 * r]     = __hip_atomic_load(&src[ridx[r]],     __ATOMIC_RELAXED, __HIP_MEMORY_SCOPE_AGENT);
                v[2 * r + 1] = __hip_atomic_load(&src[ridx[r] + 1], __ATOMIC_RELAXED, __HIP_MEMORY_SCOPE_AGENT);
            }
            bool ok = true;
            #pragma unroll
            for (int p = 0; p < 14; ++p) ok &= ((v[p] & 0xFFFFu) == exptag);
            if (ok) break;
            if (++rounds > 256) __builtin_amdgcn_s_sleep(2);   // paranoia only
        }
        // stage remote h into this parity's LDS tile (stride-2064 rows)
        #pragma unroll
        for (int r = 0; r < 7; ++r) {
            const int rbk = (nb + 1 + r) & 7;
            const int c0  = rbk * 128 + pc0;
            const uint32_t pk = (v[2 * r] >> 16) | (v[2 * r + 1] & 0xFFFF0000u);
            *(uint32_t*)(htile[cur] + pb * 2064 + c0 * 2) = pk;
        }
        __syncthreads();   // htile[cur] complete (remote staged + own from t-1)

        // --- xp prefetch for NEXT step (off the poll's critical path)
        float xnext[4];
        if (t < 511) {
            #pragma unroll
            for (int i = 0; i < 4; ++i)
                xnext[i] = out[((size_t)(gb0 + r4b + i) * 512 + (t + 1)) * 1024 + col];
        }

        // --- phase B: acc = h . Wh[col]^T over full K, 4 interleaved chains
        f32x4 a0 = (f32x4){0.f,0.f,0.f,0.f}, a1 = a0, a2 = a0, a3 = a0;
        {
            const int b_  = lane & 7;
            const int kbx = (lane >> 4) << 4;
            const uint8_t* hb = htile[cur] + b_ * 2064;
            #pragma unroll
            for (int kt = 0; kt < 32; kt += 4) {
                const bf16x8 f0 = *(const bf16x8*)(hb + (kt    ) * 64 + kbx);
                const bf16x8 f1 = *(const bf16x8*)(hb + (kt + 1) * 64 + kbx);
                const bf16x8 f2 = *(const bf16x8*)(hb + (kt + 2) * 64 + kbx);
                const bf16x8 f3 = *(const bf16x8*)(hb + (kt + 3) * 64 + kbx);
                a0 = __builtin_amdgcn_mfma_f32_16x16x32_bf16(f0, whf[kt    ], a0, 0, 0, 0);
                a1 = __builtin_amdgcn_mfma_f32_16x16x32_bf16(f1, whf[kt + 1], a1, 0, 0, 0);
                a2 = __builtin_amdgcn_mfma_f32_16x16x32_bf16(f2, whf[kt + 2], a2, 0, 0, 0);
                a3 = __builtin_amdgcn_mfma_f32_16x16x32_bf16(f3, whf[kt + 3], a3, 0, 0, 0);
            }
        }

        // --- phase C: lanes<32 publish h (critical path); lanes>=32 (which
        // hold a duplicate C fragment) write out[] concurrently.
        float pre[4], hn[4];
        #pragma unroll
        for (int i = 0; i < 4; ++i) {
            pre[i] = ((a0[i] + a1[i]) + (a2[i] + a3[i])) + xpv[i];
            hn[i]  = fast_tanh(pre[i]);
        }
        if (lane < 32) {
            if (t < 511) {
                uint32_t hu[4];
                #pragma unroll
                for (int i = 0; i < 4; ++i) hu[i] = f2bf(hn[i]);
                #pragma unroll
                for (int i = 0; i < 4; ++i)
                    __hip_atomic_store(&dst[(gb0 + r4b + i) * 1024 + col], (hu[i] << 16) | ntag,
                                       __ATOMIC_RELAXED, __HIP_MEMORY_SCOPE_AGENT);
                // own slice -> next parity's LDS tile (never crosses global)
                #pragma unroll
                for (int i = 0; i < 4; ++i)
                    *(uint16_t*)(htile[cur ^ 1] + (r4b + i) * 2064 + col * 2) = (uint16_t)hu[i];
            }
        } else {
            #pragma unroll
            for (int i = 0; i < 4; ++i) {
                out[((size_t)(gb0 + r4b + i) * 512 + t) * 1024 + col] = pre[i];
                if (t == 511) hfin[(size_t)(gb0 + r4b + i) * 1024 + col] = hn[i];
            }
        }
        #pragma unroll
        for (int i = 0; i < 4; ++i) xpv[i] = xnext[i];
    }
}

// ---------------------------------------------------------------------------
extern "C" void kernel_launch(void* const* d_in, const int* in_sizes, int n_in,
                              void* d_out, int out_size, void* d_ws, size_t ws_size,
                              hipStream_t stream) {
    const float* x   = (const float*)d_in[0];   // [64,512,512]
    const float* h0_ = (const float*)d_in[1];   // [64,1024]
    const float* Wx  = (const float*)d_in[2];   // [1024,512]
    const float* bx  = (const float*)d_in[3];   // [1024]
    const float* Wh  = (const float*)d_in[4];   // [1024,1024]
    const float* bh  = (const float*)d_in[5];   // [1024]
    float* out  = (float*)d_out;                         // [64,512,1024] pre
    float* hfin = out + (size_t)64 * 512 * 1024;         // [64,1024]
    uint32_t* hbuf = (uint32_t*)d_ws;                    // [2][64][1024] u32 = 512 KB

    // invalidate all tags (0xFFFF matches no step tag 1..513)
    hipMemsetAsync(d_ws, 0xFF, (size_t)2 * 64 * 1024 * sizeof(uint32_t), stream);

    xproj_gemm<<<dim3(2048), dim3(256), 0, stream>>>(x, Wx, bx, bh, out);
    rnn_scan<<<dim3(64), dim3(512), 0, stream>>>(h0_, Wh, out, hfin, hbuf);
}